// Round 7
// baseline (200.921 us; speedup 1.0000x reference)
//
#include <hip/hip_runtime.h>
#include <math.h>

#define BATCH_ 65536
#define NN 512
#define KK 48
#define OFF_HHRE (2*BATCH_*KK)            // 6291456
#define OFF_HHIM (OFF_HHRE + BATCH_*NN)   // 39845888

typedef float f32x4 __attribute__((ext_vector_type(4)));
typedef int   i32x4 __attribute__((ext_vector_type(4)));
typedef short bf16x8 __attribute__((ext_vector_type(8)));

// ---- ws layout (byte offsets) ----
#define WS_PB    0u         // 2*32*2*512 bf16 = 262144 B
#define WS_PA    262144u    // 2*16*3*512 bf16 =  98304 B (ends 360448)
#define WS_SIGP  393216u    // 256 f32
#define WS_SIGMA 394240u    // 1 f32
#define WS_BPART 395264u    // 4096*2 f32 = 32 KB (ends 428032)
#define WS_BVAL  428032u    // 2 f32

__device__ __forceinline__ unsigned short f2bf(float x) {
  unsigned u = __builtin_bit_cast(unsigned, x);
  unsigned r = (u + 0x7fffu + ((u >> 16) & 1u)) >> 16;
  return (unsigned short)r;
}
__device__ __forceinline__ int pack2bf(float a, float b) {
  return (int)f2bf(a) | ((int)f2bf(b) << 16);
}
__device__ __forceinline__ i32x4 pack8bf(f32x4 a, f32x4 b) {
  i32x4 r;
  r.x = pack2bf(a.x, a.y); r.y = pack2bf(a.z, a.w);
  r.z = pack2bf(b.x, b.y); r.w = pack2bf(b.z, b.w);
  return r;
}
__device__ __forceinline__ float waveRed(float v) {
#pragma unroll
  for (int o = 32; o > 0; o >>= 1) v += __shfl_down(v, o);
  return v;
}

// compiler-scheduled MFMA
#define MFMA(acc, A, B) \
  acc = __builtin_amdgcn_mfma_f32_16x16x32_bf16( \
      __builtin_bit_cast(bf16x8, A), __builtin_bit_cast(bf16x8, B), acc, 0, 0, 0)

// ---------------- pack B/A into fragment-ordered bf16 (layout unchanged) ----
// PB[mat][nt:32][ks:2][lane:64][j:8] = B_mat[nt*16 + (l&15)][ks*32+(l>>4)*8+j], 0 pad k>=48
// PA[mat][ks:16][ct:3][lane:64][j:8] = A_mat[ks*32+(l>>4)*8+j][ct*16 + (l&15)]
__global__ void lamp_pack(const float* __restrict__ Bre, const float* __restrict__ Bim,
                          const float* __restrict__ Are, const float* __restrict__ Aim,
                          unsigned short* __restrict__ pb, unsigned short* __restrict__ pa)
{
  int i = blockIdx.x * 256 + threadIdx.x;
  const int NPB = 2*32*2*512;   // 65536
  const int NPA = 2*16*3*512;   // 49152
  if (i < NPB) {
    int j = i & 7, l = (i >> 3) & 63, ks = (i >> 9) & 1, nt = (i >> 10) & 31, mat = i >> 15;
    int k = ks*32 + (l >> 4)*8 + j;
    int n = nt*16 + (l & 15);
    float v = 0.f;
    if (k < KK) v = mat ? Bim[n*KK + k] : Bre[n*KK + k];
    pb[i] = f2bf(v);
  } else if (i < NPB + NPA) {
    int i2 = i - NPB;
    int j = i2 & 7, l = (i2 >> 3) & 63;
    int rem = i2 >> 9;          // (mat*16+ks)*3 + ct
    int ct = rem % 3; rem /= 3;
    int ks = rem & 15; int mat = rem >> 4;
    int k = ks*32 + (l >> 4)*8 + j;
    int c = ct*16 + (l & 15);
    float v = mat ? Aim[k*KK + c] : Are[k*KK + c];
    pa[i2] = f2bf(v);
  }
}

// ---------------- sigma ----------------
__global__ void lamp_sig(const float* __restrict__ zr, const float* __restrict__ zi,
                         float* __restrict__ part)
{
  const int n4 = BATCH_*KK/4;
  const f32x4* a = (const f32x4*)zr; const f32x4* b = (const f32x4*)zi;
  float s = 0.f;
  for (int i = blockIdx.x*blockDim.x + threadIdx.x; i < n4; i += gridDim.x*blockDim.x) {
    f32x4 x = a[i]; s += x.x*x.x + x.y*x.y + x.z*x.z + x.w*x.w;
    f32x4 y = b[i]; s += y.x*y.x + y.y*y.y + y.z*y.z + y.w*y.w;
  }
  __shared__ float red[4];
  s = waveRed(s);
  int wave = threadIdx.x >> 6, lane = threadIdx.x & 63;
  if (lane == 0) red[wave] = s;
  __syncthreads();
  if (threadIdx.x == 0) part[blockIdx.x] = red[0]+red[1]+red[2]+red[3];
}

__global__ void lamp_sigfin(const float* __restrict__ part, float* __restrict__ sig)
{
  float s = part[threadIdx.x];   // 256 partials
  __shared__ float red[4];
  s = waveRed(s);
  int wave = threadIdx.x >> 6, lane = threadIdx.x & 63;
  if (lane == 0) red[wave] = s;
  __syncthreads();
  if (threadIdx.x == 0) sig[0] = sqrtf(red[0]+red[1]+red[2]+red[3]) / sqrtf((float)KK);
}

// ---------------- main fused kernel (R7: R6 + per-block phase stagger) -----
// All blocks previously read the SAME 14KB of frag data per iteration in
// lockstep -> L2-slice hotspot. Stagger: block b processes pair-tiles in
// rotated order p = (b + t) & 15, spreading frag requests over 16 windows.
// GEMM2 k-accumulation order rotates per block; per-wave summation order is
// fixed -> deterministic output.
__global__ __launch_bounds__(256, 3) void lamp_main(
    const float* __restrict__ zre, const float* __restrict__ zim,
    const float* __restrict__ Hre, const float* __restrict__ Him,
    const unsigned short* __restrict__ pb, const unsigned short* __restrict__ pa,
    const float* __restrict__ sigp, const float* __restrict__ theta,
    float* __restrict__ out, float* __restrict__ bpart)
{
  const int tid = threadIdx.x;
  const int wave = tid >> 6, lane = tid & 63;
  const int l15 = lane & 15, lg = lane >> 4;
  const int rbase = blockIdx.x * 64 + wave * 16;
  const int myrow = rbase + l15;
  const int phase = blockIdx.x & 15;

  const float t0 = theta[0], t1 = theta[1], t2 = theta[2];
  const float sigma = sigp[0];
  const float s2 = (t0 * sigma) * (t0 * sigma);
  const float inv_s2 = 1.0f / s2;
  const float nhalf_inv_s2 = -0.5f * inv_s2;

  // z fragments (B operand of GEMM1'), K padded 48->64; lane: z[myrow][8lg+j]
  i32x4 zr[2], zi[2];
  {
    const float* pr = zre + (size_t)myrow * KK;
    const float* pi = zim + (size_t)myrow * KK;
#pragma unroll
    for (int ks = 0; ks < 2; ++ks) {
      const int k0 = ks*32 + lg*8;
      f32x4 a0 = {0,0,0,0}, a1 = {0,0,0,0}, b0 = {0,0,0,0}, b1 = {0,0,0,0};
      if (k0 < KK) {
        a0 = *(const f32x4*)(pr + k0); a1 = *(const f32x4*)(pr + k0 + 4);
        b0 = *(const f32x4*)(pi + k0); b1 = *(const f32x4*)(pi + k0 + 4);
      }
      zr[ks] = pack8bf(a0, a1);
      zi[ks] = pack8bf(b0, b1);
    }
  }

  const i32x4* pb4 = (const i32x4*)pb;
  const i32x4* pa4 = (const i32x4*)pa;

  // per-lane row-slice bases (f32x4 at col p*32 + lg*4)
  const float* hrB = Hre + (size_t)myrow * NN + lg*4;
  const float* hiB = Him + (size_t)myrow * NN + lg*4;
  float* oRB = out + OFF_HHRE + (size_t)myrow * NN + lg*4;
  float* oIB = out + OFF_HHIM + (size_t)myrow * NN + lg*4;

  f32x4 ahR[3], ahI[3];
#pragma unroll
  for (int c = 0; c < 3; ++c) { ahR[c] = (f32x4){0,0,0,0}; ahI[c] = (f32x4){0,0,0,0}; }

  float dsr = 0.f, dsi = 0.f;
  const bool hi2 = (lg >= 2);                 // target wants pair-tile 1?
  const int srcA = l15 + ((lane & 16) << 1);  // l15 + 32*(lg&1)
  const int srcB = srcA + 16;

#pragma unroll 1
  for (int t = 0; t < 16; ++t) {
    const int p = (phase + t) & 15;           // staggered pair index
    const int n0 = 2*p, n1 = n0 + 1;

    // H loads for the pair (consumed after the 16 MFMAs below)
    f32x4 hR0 = *(const f32x4*)(hrB + 32*p);
    f32x4 hR1 = *(const f32x4*)(hrB + 32*p + 16);
    f32x4 hI0 = *(const f32x4*)(hiB + 32*p);
    f32x4 hI1 = *(const f32x4*)(hiB + 32*p + 16);

    i32x4 nzi0 = zi[0] ^ 0x80008000, nzi1 = zi[1] ^ 0x80008000;

    // ---- GEMM1' tile n0 ----
    f32x4 aR0 = (f32x4){0,0,0,0}, aI0 = (f32x4){0,0,0,0};
    {
      i32x4 b0 = pb4[(n0*2 + 0)*64 + lane];
      i32x4 b1 = pb4[(n0*2 + 1)*64 + lane];
      i32x4 c0 = pb4[((32 + n0)*2 + 0)*64 + lane];
      i32x4 c1 = pb4[((32 + n0)*2 + 1)*64 + lane];
      MFMA(aR0, b0, zr[0]); MFMA(aR0, b1, zr[1]);
      MFMA(aR0, c0, nzi0);  MFMA(aR0, c1, nzi1);
      MFMA(aI0, b0, zi[0]); MFMA(aI0, b1, zi[1]);
      MFMA(aI0, c0, zr[0]); MFMA(aI0, c1, zr[1]);
    }
    // ---- GEMM1' tile n1 ----
    f32x4 aR1 = (f32x4){0,0,0,0}, aI1 = (f32x4){0,0,0,0};
    {
      i32x4 b0 = pb4[(n1*2 + 0)*64 + lane];
      i32x4 b1 = pb4[(n1*2 + 1)*64 + lane];
      i32x4 c0 = pb4[((32 + n1)*2 + 0)*64 + lane];
      i32x4 c1 = pb4[((32 + n1)*2 + 1)*64 + lane];
      MFMA(aR1, b0, zr[0]); MFMA(aR1, b1, zr[1]);
      MFMA(aR1, c0, nzi0);  MFMA(aR1, c1, nzi1);
      MFMA(aI1, b0, zi[0]); MFMA(aI1, b1, zi[1]);
      MFMA(aI1, c0, zr[0]); MFMA(aI1, c1, zr[1]);
    }

    // ---- fused elementwise: R = H + Z, shrink, deriv (in-register) ----
    f32x4 re0 = aR0 + hR0, im0 = aI0 + hI0;
    f32x4 re1 = aR1 + hR1, im1 = aI1 + hI1;
    f32x4 hhr0, hhi0, hhr1, hhi1;
#pragma unroll
    for (int c = 0; c < 4; ++c) {
      float x;
      x = re0[c]; { float e = __expf(x*x*nhalf_inv_s2); float te = t2*e;
        hhr0[c] = t1*x + x*te; dsr += t1 + te*(1.f - x*x*inv_s2); }
      x = im0[c]; { float e = __expf(x*x*nhalf_inv_s2); float te = t2*e;
        hhi0[c] = t1*x + x*te; dsi += t1 + te*(1.f - x*x*inv_s2); }
      x = re1[c]; { float e = __expf(x*x*nhalf_inv_s2); float te = t2*e;
        hhr1[c] = t1*x + x*te; dsr += t1 + te*(1.f - x*x*inv_s2); }
      x = im1[c]; { float e = __expf(x*x*nhalf_inv_s2); float te = t2*e;
        hhi1[c] = t1*x + x*te; dsi += t1 + te*(1.f - x*x*inv_s2); }
    }
    __builtin_nontemporal_store(hhr0, (f32x4*)(oRB + 32*p));
    __builtin_nontemporal_store(hhr1, (f32x4*)(oRB + 32*p + 16));
    __builtin_nontemporal_store(hhi0, (f32x4*)(oIB + 32*p));
    __builtin_nontemporal_store(hhi1, (f32x4*)(oIB + 32*p + 16));

    // ---- 4-lane exchange: acc row-slices -> GEMM2' B-operand frags ----
    f32x4 selR, selI;
#pragma unroll
    for (int c = 0; c < 4; ++c) {
      selR[c] = hi2 ? hhr1[c] : hhr0[c];
      selI[c] = hi2 ? hhi1[c] : hhi0[c];
    }
    f32x4 w0, w1, v0, v1;
#pragma unroll
    for (int c = 0; c < 4; ++c) {
      w0[c] = __shfl(selR[c], srcA, 64);
      w1[c] = __shfl(selR[c], srcB, 64);
      v0[c] = __shfl(selI[c], srcA, 64);
      v1[c] = __shfl(selI[c], srcB, 64);
    }
    i32x4 hhRf = pack8bf(w0, w1);
    i32x4 hhIf = pack8bf(v0, v1);

    // ---- GEMM2' partial: k-slice p (cols 32p..32p+31) ----
#pragma unroll
    for (int ct = 0; ct < 3; ++ct) {
      i32x4 par = pa4[(p*3 + ct)*64 + lane];
      i32x4 pai = pa4[((16 + p)*3 + ct)*64 + lane];
      i32x4 nai = pai ^ 0x80008000;
      MFMA(ahR[ct], par, hhRf);
      MFMA(ahR[ct], nai, hhIf);
      MFMA(ahI[ct], pai, hhRf);
      MFMA(ahI[ct], par, hhIf);
    }
  }

  // epilogue: h stored as per-lane f32x4 row slices
#pragma unroll
  for (int ct = 0; ct < 3; ++ct) {
    *(f32x4*)(out + (size_t)myrow*KK + ct*16 + lg*4) = ahR[ct];
    *(f32x4*)(out + (size_t)(BATCH_*KK) + (size_t)myrow*KK + ct*16 + lg*4) = ahI[ct];
  }

  // per-wave deriv partials (4096 waves)
  float rr = waveRed(dsr), ri = waveRed(dsi);
  if (lane == 0) {
    const int w = blockIdx.x * 4 + wave;
    bpart[2*w]     = rr;
    bpart[2*w + 1] = ri;
  }
}

// ---------------- b reduce (4096 wave-partials) ----------------
__global__ void lamp_bred(const float* __restrict__ bpart, float* __restrict__ bval)
{
  float sr = 0.f, si = 0.f;
  for (int m = threadIdx.x; m < 4096; m += 256) { sr += bpart[2*m]; si += bpart[2*m + 1]; }
  __shared__ float red[8];
  sr = waveRed(sr); si = waveRed(si);
  int wave = threadIdx.x >> 6, lane = threadIdx.x & 63;
  if (lane == 0) { red[wave] = sr; red[4 + wave] = si; }
  __syncthreads();
  if (threadIdx.x == 0) {
    bval[0] = (red[0]+red[1]+red[2]+red[3]) / (float)KK;
    bval[1] = (red[4]+red[5]+red[6]+red[7]) / (float)KK;
  }
}

// ---------------- z_new (in-place over parked h) ----------------
__global__ void lamp_znew(const float* __restrict__ ur, const float* __restrict__ ui,
                          const float* __restrict__ zr, const float* __restrict__ zi,
                          const float* __restrict__ bval, float* __restrict__ out)
{
  const float br = bval[0], bi = bval[1];
  const int n4 = BATCH_*KK/4;
  const f32x4* u4r = (const f32x4*)ur; const f32x4* u4i = (const f32x4*)ui;
  const f32x4* z4r = (const f32x4*)zr; const f32x4* z4i = (const f32x4*)zi;
  f32x4* o4r = (f32x4*)out;
  f32x4* o4i = (f32x4*)(out + BATCH_*KK);
  for (int i = blockIdx.x*blockDim.x + threadIdx.x; i < n4; i += gridDim.x*blockDim.x) {
    f32x4 h = o4r[i];
    o4r[i] = u4r[i] - h + br * z4r[i];
    f32x4 h2 = o4i[i];
    o4i[i] = u4i[i] - h2 + bi * z4i[i];
  }
}

extern "C" void kernel_launch(void* const* d_in, const int* in_sizes, int n_in,
                              void* d_out, int out_size, void* d_ws, size_t ws_size,
                              hipStream_t stream)
{
  const float* ur  = (const float*)d_in[0];
  const float* ui  = (const float*)d_in[1];
  const float* zr  = (const float*)d_in[2];
  const float* zi  = (const float*)d_in[3];
  const float* Hr  = (const float*)d_in[4];
  const float* Hi  = (const float*)d_in[5];
  const float* Bre = (const float*)d_in[6];
  const float* Bim = (const float*)d_in[7];
  const float* Are = (const float*)d_in[8];
  const float* Aim = (const float*)d_in[9];
  const float* th  = (const float*)d_in[10];
  float* out = (float*)d_out;
  char* ws = (char*)d_ws;
  unsigned short* pb  = (unsigned short*)(ws + WS_PB);
  unsigned short* pa  = (unsigned short*)(ws + WS_PA);
  float* sigp  = (float*)(ws + WS_SIGP);
  float* sigv  = (float*)(ws + WS_SIGMA);
  float* bpart = (float*)(ws + WS_BPART);
  float* bval  = (float*)(ws + WS_BVAL);

  hipLaunchKernelGGL(lamp_pack,   dim3(448),  dim3(256), 0, stream, Bre, Bim, Are, Aim, pb, pa);
  hipLaunchKernelGGL(lamp_sig,    dim3(256),  dim3(256), 0, stream, zr, zi, sigp);
  hipLaunchKernelGGL(lamp_sigfin, dim3(1),    dim3(256), 0, stream, sigp, sigv);
  hipLaunchKernelGGL(lamp_main,   dim3(1024), dim3(256), 0, stream,
                     zr, zi, Hr, Hi, pb, pa, sigv, th, out, bpart);
  hipLaunchKernelGGL(lamp_bred,   dim3(1),    dim3(256), 0, stream, bpart, bval);
  hipLaunchKernelGGL(lamp_znew,   dim3(1024), dim3(256), 0, stream, ur, ui, zr, zi, bval, out);
}

// Round 8
// 169.366 us; speedup vs baseline: 1.1863x; 1.1863x over previous
//
#include <hip/hip_runtime.h>
#include <math.h>

#define BATCH_ 65536
#define NN 512
#define KK 48
#define OFF_HHRE (2*BATCH_*KK)            // 6291456
#define OFF_HHIM (OFF_HHRE + BATCH_*NN)   // 39845888

typedef float f32x4 __attribute__((ext_vector_type(4)));
typedef int   i32x4 __attribute__((ext_vector_type(4)));
typedef short bf16x8 __attribute__((ext_vector_type(8)));

// ---- ws layout (byte offsets) ----
// FR: 16 pair-chunks x 14336 B = 229376 B. Per chunk: j=0..13 slots of
// [64 lanes x 16B]: j0..3 = tile n0 {re_ks0, re_ks1, im_ks0, im_ks1},
// j4..7 = tile n1 same, j8..13 = GEMM2 {par,pai} x ct=0..2.
#define WS_FR    0u
#define WS_SIGP  262144u    // 256 f32
#define WS_SIGMA 263168u    // 1 f32
#define WS_BPART 264192u    // 4096*2 f32 = 32 KB
#define WS_BVAL  296960u    // 2 f32

__device__ __forceinline__ unsigned short f2bf(float x) {
  unsigned u = __builtin_bit_cast(unsigned, x);
  unsigned r = (u + 0x7fffu + ((u >> 16) & 1u)) >> 16;
  return (unsigned short)r;
}
__device__ __forceinline__ int pack2bf(float a, float b) {
  return (int)f2bf(a) | ((int)f2bf(b) << 16);
}
__device__ __forceinline__ i32x4 pack8bf(f32x4 a, f32x4 b) {
  i32x4 r;
  r.x = pack2bf(a.x, a.y); r.y = pack2bf(a.z, a.w);
  r.z = pack2bf(b.x, b.y); r.w = pack2bf(b.z, b.w);
  return r;
}
__device__ __forceinline__ float waveRed(float v) {
#pragma unroll
  for (int o = 32; o > 0; o >>= 1) v += __shfl_down(v, o);
  return v;
}

#define MFMA(acc, A, B) \
  acc = __builtin_amdgcn_mfma_f32_16x16x32_bf16( \
      __builtin_bit_cast(bf16x8, A), __builtin_bit_cast(bf16x8, B), acc, 0, 0, 0)

// ---------------- pack frag table (contiguous per pair-tile chunk) ---------
__global__ void lamp_pack(const float* __restrict__ Bre, const float* __restrict__ Bim,
                          const float* __restrict__ Are, const float* __restrict__ Aim,
                          unsigned short* __restrict__ fr)
{
  int i = blockIdx.x * 256 + threadIdx.x;       // 448*256 = 114688 exact
  int jj = i & 7, l = (i >> 3) & 63;
  int idx = i >> 9;                             // 0..223
  int p = idx / 14, j = idx % 14;
  float v;
  if (j < 8) {
    int nt = 2*p + (j >> 2);
    int mat = (j >> 1) & 1;
    int ks = j & 1;
    int k = ks*32 + (l >> 4)*8 + jj;
    int n = nt*16 + (l & 15);
    v = (k < KK) ? (mat ? Bim[n*KK + k] : Bre[n*KK + k]) : 0.f;
  } else {
    int jp = j - 8;
    int ct = jp >> 1, m = jp & 1;
    int k = p*32 + (l >> 4)*8 + jj;
    int c = ct*16 + (l & 15);
    v = m ? Aim[k*KK + c] : Are[k*KK + c];
  }
  fr[i] = f2bf(v);
}

// ---------------- sigma ----------------
__global__ void lamp_sig(const float* __restrict__ zr, const float* __restrict__ zi,
                         float* __restrict__ part)
{
  const int n4 = BATCH_*KK/4;
  const f32x4* a = (const f32x4*)zr; const f32x4* b = (const f32x4*)zi;
  float s = 0.f;
  for (int i = blockIdx.x*blockDim.x + threadIdx.x; i < n4; i += gridDim.x*blockDim.x) {
    f32x4 x = a[i]; s += x.x*x.x + x.y*x.y + x.z*x.z + x.w*x.w;
    f32x4 y = b[i]; s += y.x*y.x + y.y*y.y + y.z*y.z + y.w*y.w;
  }
  __shared__ float red[4];
  s = waveRed(s);
  int wave = threadIdx.x >> 6, lane = threadIdx.x & 63;
  if (lane == 0) red[wave] = s;
  __syncthreads();
  if (threadIdx.x == 0) part[blockIdx.x] = red[0]+red[1]+red[2]+red[3];
}

__global__ void lamp_sigfin(const float* __restrict__ part, float* __restrict__ sig)
{
  float s = part[threadIdx.x];   // 256 partials
  __shared__ float red[4];
  s = waveRed(s);
  int wave = threadIdx.x >> 6, lane = threadIdx.x & 63;
  if (lane == 0) red[wave] = s;
  __syncthreads();
  if (threadIdx.x == 0) sig[0] = sqrtf(red[0]+red[1]+red[2]+red[3]) / sqrtf((float)KK);
}

// ---------------- main fused kernel (R8: block-shared LDS frag staging) ----
// All 4 waves of a block consume IDENTICAL frag data -> stage each 14336 B
// pair-chunk into LDS once per block (async global_load_lds, double-buffered),
// read via ds_read_b128. Kills the per-wave 14 KB/iter L1-miss stream that
// was invariant across R1-R7. One __syncthreads per iteration (its implicit
// vmcnt drain covers gload_lds completion).
__global__ __launch_bounds__(256, 3) void lamp_main(
    const float* __restrict__ zre, const float* __restrict__ zim,
    const float* __restrict__ Hre, const float* __restrict__ Him,
    const unsigned short* __restrict__ fr,
    const float* __restrict__ sigp, const float* __restrict__ theta,
    float* __restrict__ out, float* __restrict__ bpart)
{
  __shared__ __align__(16) i32x4 fb[2][896];   // 2 x 14336 B

  const int tid = threadIdx.x;
  const int wave = tid >> 6, lane = tid & 63;
  const int l15 = lane & 15, lg = lane >> 4;
  const int rbase = blockIdx.x * 64 + wave * 16;
  const int myrow = rbase + l15;
  const int phase = blockIdx.x & 15;
  const char* frc = (const char*)fr;

#define STAGE(bi, pp) do { \
    const char* gsrc_ = frc + (size_t)(pp)*14336 + wave*4096 + lane*16; \
    char* ldst_ = ((char*)&fb[bi][0]) + wave*4096 + lane*16; \
    const int ng_ = (wave < 3) ? 4 : 2; \
    for (int s_ = 0; s_ < ng_; ++s_) \
      __builtin_amdgcn_global_load_lds( \
          (const __attribute__((address_space(1))) void*)(gsrc_ + s_*1024), \
          (__attribute__((address_space(3))) void*)(ldst_ + s_*1024), 16, 0, 0); \
  } while (0)

  const float t0 = theta[0], t1 = theta[1], t2 = theta[2];
  const float sigma = sigp[0];
  const float s2 = (t0 * sigma) * (t0 * sigma);
  const float inv_s2 = 1.0f / s2;
  const float nhalf_inv_s2 = -0.5f * inv_s2;

  // z fragments (B operand of GEMM1'), K padded 48->64; lane: z[myrow][8lg+j]
  i32x4 zr[2], zi[2];
  {
    const float* pr = zre + (size_t)myrow * KK;
    const float* pi = zim + (size_t)myrow * KK;
#pragma unroll
    for (int ks = 0; ks < 2; ++ks) {
      const int k0 = ks*32 + lg*8;
      f32x4 a0 = {0,0,0,0}, a1 = {0,0,0,0}, b0 = {0,0,0,0}, b1 = {0,0,0,0};
      if (k0 < KK) {
        a0 = *(const f32x4*)(pr + k0); a1 = *(const f32x4*)(pr + k0 + 4);
        b0 = *(const f32x4*)(pi + k0); b1 = *(const f32x4*)(pi + k0 + 4);
      }
      zr[ks] = pack8bf(a0, a1);
      zi[ks] = pack8bf(b0, b1);
    }
  }

  // per-lane row-slice bases (f32x4 at col p*32 + lg*4)
  const float* hrB = Hre + (size_t)myrow * NN + lg*4;
  const float* hiB = Him + (size_t)myrow * NN + lg*4;
  float* oRB = out + OFF_HHRE + (size_t)myrow * NN + lg*4;
  float* oIB = out + OFF_HHIM + (size_t)myrow * NN + lg*4;

  f32x4 ahR[3], ahI[3];
#pragma unroll
  for (int c = 0; c < 3; ++c) { ahR[c] = (f32x4){0,0,0,0}; ahI[c] = (f32x4){0,0,0,0}; }

  float dsr = 0.f, dsi = 0.f;
  const bool hi2 = (lg >= 2);
  const int srcA = l15 + ((lane & 16) << 1);
  const int srcB = srcA + 16;

  // prologue: stage chunk for t=0
  STAGE(0, phase);
  __syncthreads();

#pragma unroll 1
  for (int t = 0; t < 16; ++t) {
    const int cur = t & 1;
    const int p = (phase + t) & 15;

    // H loads (HBM, deepest latency — issue first)
    f32x4 hR0 = *(const f32x4*)(hrB + 32*p);
    f32x4 hR1 = *(const f32x4*)(hrB + 32*p + 16);
    f32x4 hI0 = *(const f32x4*)(hiB + 32*p);
    f32x4 hI1 = *(const f32x4*)(hiB + 32*p + 16);

    // async-stage next chunk into the other buffer
    if (t < 15) STAGE(cur ^ 1, (phase + t + 1) & 15);

    const i32x4* fbc = &fb[cur][0];
    i32x4 nzi0 = zi[0] ^ 0x80008000, nzi1 = zi[1] ^ 0x80008000;

    // ---- GEMM1' tile n0 (frags from LDS) ----
    f32x4 aR0 = (f32x4){0,0,0,0}, aI0 = (f32x4){0,0,0,0};
    {
      i32x4 b0 = fbc[0*64 + lane];
      i32x4 b1 = fbc[1*64 + lane];
      i32x4 c0 = fbc[2*64 + lane];
      i32x4 c1 = fbc[3*64 + lane];
      MFMA(aR0, b0, zr[0]); MFMA(aR0, b1, zr[1]);
      MFMA(aR0, c0, nzi0);  MFMA(aR0, c1, nzi1);
      MFMA(aI0, b0, zi[0]); MFMA(aI0, b1, zi[1]);
      MFMA(aI0, c0, zr[0]); MFMA(aI0, c1, zr[1]);
    }
    // ---- GEMM1' tile n1 ----
    f32x4 aR1 = (f32x4){0,0,0,0}, aI1 = (f32x4){0,0,0,0};
    {
      i32x4 b0 = fbc[4*64 + lane];
      i32x4 b1 = fbc[5*64 + lane];
      i32x4 c0 = fbc[6*64 + lane];
      i32x4 c1 = fbc[7*64 + lane];
      MFMA(aR1, b0, zr[0]); MFMA(aR1, b1, zr[1]);
      MFMA(aR1, c0, nzi0);  MFMA(aR1, c1, nzi1);
      MFMA(aI1, b0, zi[0]); MFMA(aI1, b1, zi[1]);
      MFMA(aI1, c0, zr[0]); MFMA(aI1, c1, zr[1]);
    }

    // ---- fused elementwise: R = H + Z, shrink, deriv ----
    f32x4 re0 = aR0 + hR0, im0 = aI0 + hI0;
    f32x4 re1 = aR1 + hR1, im1 = aI1 + hI1;
    f32x4 hhr0, hhi0, hhr1, hhi1;
#pragma unroll
    for (int c = 0; c < 4; ++c) {
      float x;
      x = re0[c]; { float e = __expf(x*x*nhalf_inv_s2); float te = t2*e;
        hhr0[c] = t1*x + x*te; dsr += t1 + te*(1.f - x*x*inv_s2); }
      x = im0[c]; { float e = __expf(x*x*nhalf_inv_s2); float te = t2*e;
        hhi0[c] = t1*x + x*te; dsi += t1 + te*(1.f - x*x*inv_s2); }
      x = re1[c]; { float e = __expf(x*x*nhalf_inv_s2); float te = t2*e;
        hhr1[c] = t1*x + x*te; dsr += t1 + te*(1.f - x*x*inv_s2); }
      x = im1[c]; { float e = __expf(x*x*nhalf_inv_s2); float te = t2*e;
        hhi1[c] = t1*x + x*te; dsi += t1 + te*(1.f - x*x*inv_s2); }
    }
    __builtin_nontemporal_store(hhr0, (f32x4*)(oRB + 32*p));
    __builtin_nontemporal_store(hhr1, (f32x4*)(oRB + 32*p + 16));
    __builtin_nontemporal_store(hhi0, (f32x4*)(oIB + 32*p));
    __builtin_nontemporal_store(hhi1, (f32x4*)(oIB + 32*p + 16));

    // ---- 4-lane exchange: acc row-slices -> GEMM2' B-operand frags ----
    f32x4 selR, selI;
#pragma unroll
    for (int c = 0; c < 4; ++c) {
      selR[c] = hi2 ? hhr1[c] : hhr0[c];
      selI[c] = hi2 ? hhi1[c] : hhi0[c];
    }
    f32x4 w0, w1, v0, v1;
#pragma unroll
    for (int c = 0; c < 4; ++c) {
      w0[c] = __shfl(selR[c], srcA, 64);
      w1[c] = __shfl(selR[c], srcB, 64);
      v0[c] = __shfl(selI[c], srcA, 64);
      v1[c] = __shfl(selI[c], srcB, 64);
    }
    i32x4 hhRf = pack8bf(w0, w1);
    i32x4 hhIf = pack8bf(v0, v1);

    // ---- GEMM2' partial: k-slice p ----
#pragma unroll
    for (int ct = 0; ct < 3; ++ct) {
      i32x4 par = fbc[(8 + 2*ct)*64 + lane];
      i32x4 pai = fbc[(9 + 2*ct)*64 + lane];
      i32x4 nai = pai ^ 0x80008000;
      MFMA(ahR[ct], par, hhRf);
      MFMA(ahR[ct], nai, hhIf);
      MFMA(ahI[ct], pai, hhRf);
      MFMA(ahI[ct], par, hhIf);
    }

    // barrier: implicit full vmcnt drain covers the async stage; also
    // guarantees all waves finished reading fb[cur] before it is restaged.
    __syncthreads();
  }

  // epilogue: h stored as per-lane f32x4 row slices
#pragma unroll
  for (int ct = 0; ct < 3; ++ct) {
    *(f32x4*)(out + (size_t)myrow*KK + ct*16 + lg*4) = ahR[ct];
    *(f32x4*)(out + (size_t)(BATCH_*KK) + (size_t)myrow*KK + ct*16 + lg*4) = ahI[ct];
  }

  // per-wave deriv partials (4096 waves)
  float rr = waveRed(dsr), ri = waveRed(dsi);
  if (lane == 0) {
    const int w = blockIdx.x * 4 + wave;
    bpart[2*w]     = rr;
    bpart[2*w + 1] = ri;
  }
#undef STAGE
}

// ---------------- b reduce (4096 wave-partials) ----------------
__global__ void lamp_bred(const float* __restrict__ bpart, float* __restrict__ bval)
{
  float sr = 0.f, si = 0.f;
  for (int m = threadIdx.x; m < 4096; m += 256) { sr += bpart[2*m]; si += bpart[2*m + 1]; }
  __shared__ float red[8];
  sr = waveRed(sr); si = waveRed(si);
  int wave = threadIdx.x >> 6, lane = threadIdx.x & 63;
  if (lane == 0) { red[wave] = sr; red[4 + wave] = si; }
  __syncthreads();
  if (threadIdx.x == 0) {
    bval[0] = (red[0]+red[1]+red[2]+red[3]) / (float)KK;
    bval[1] = (red[4]+red[5]+red[6]+red[7]) / (float)KK;
  }
}

// ---------------- z_new (in-place over parked h) ----------------
__global__ void lamp_znew(const float* __restrict__ ur, const float* __restrict__ ui,
                          const float* __restrict__ zr, const float* __restrict__ zi,
                          const float* __restrict__ bval, float* __restrict__ out)
{
  const float br = bval[0], bi = bval[1];
  const int n4 = BATCH_*KK/4;
  const f32x4* u4r = (const f32x4*)ur; const f32x4* u4i = (const f32x4*)ui;
  const f32x4* z4r = (const f32x4*)zr; const f32x4* z4i = (const f32x4*)zi;
  f32x4* o4r = (f32x4*)out;
  f32x4* o4i = (f32x4*)(out + BATCH_*KK);
  for (int i = blockIdx.x*blockDim.x + threadIdx.x; i < n4; i += gridDim.x*blockDim.x) {
    f32x4 h = o4r[i];
    o4r[i] = u4r[i] - h + br * z4r[i];
    f32x4 h2 = o4i[i];
    o4i[i] = u4i[i] - h2 + bi * z4i[i];
  }
}

extern "C" void kernel_launch(void* const* d_in, const int* in_sizes, int n_in,
                              void* d_out, int out_size, void* d_ws, size_t ws_size,
                              hipStream_t stream)
{
  const float* ur  = (const float*)d_in[0];
  const float* ui  = (const float*)d_in[1];
  const float* zr  = (const float*)d_in[2];
  const float* zi  = (const float*)d_in[3];
  const float* Hr  = (const float*)d_in[4];
  const float* Hi  = (const float*)d_in[5];
  const float* Bre = (const float*)d_in[6];
  const float* Bim = (const float*)d_in[7];
  const float* Are = (const float*)d_in[8];
  const float* Aim = (const float*)d_in[9];
  const float* th  = (const float*)d_in[10];
  float* out = (float*)d_out;
  char* ws = (char*)d_ws;
  unsigned short* fr = (unsigned short*)(ws + WS_FR);
  float* sigp  = (float*)(ws + WS_SIGP);
  float* sigv  = (float*)(ws + WS_SIGMA);
  float* bpart = (float*)(ws + WS_BPART);
  float* bval  = (float*)(ws + WS_BVAL);

  hipLaunchKernelGGL(lamp_pack,   dim3(448),  dim3(256), 0, stream, Bre, Bim, Are, Aim, fr);
  hipLaunchKernelGGL(lamp_sig,    dim3(256),  dim3(256), 0, stream, zr, zi, sigp);
  hipLaunchKernelGGL(lamp_sigfin, dim3(1),    dim3(256), 0, stream, sigp, sigv);
  hipLaunchKernelGGL(lamp_main,   dim3(1024), dim3(256), 0, stream,
                     zr, zi, Hr, Hi, fr, sigv, th, out, bpart);
  hipLaunchKernelGGL(lamp_bred,   dim3(1),    dim3(256), 0, stream, bpart, bval);
  hipLaunchKernelGGL(lamp_znew,   dim3(1024), dim3(256), 0, stream, ur, ui, zr, zi, bval, out);
}